// Round 9
// baseline (204.169 us; speedup 1.0000x reference)
//
#include <hip/hip_runtime.h>
#include <math.h>

#define NF   39
#define NB   16384
#define NVOC 10000

typedef unsigned short u16;
typedef unsigned int   u32;
typedef float f32x4 __attribute__((ext_vector_type(4)));
typedef short s16x8 __attribute__((ext_vector_type(8)));

// ---- d_ws layout (u16 units) ----
// [0, E3_U16): E3 activations, A-fragment tiles: (st, ks=f) -> 512 u16
// [E3_U16 ...): weights as 512-u16 fragment tiles:
//   12 attn mats (q,k,v,r × 3 layers) × 2 tiles = 12288   (wq pre-scaled by log2e)
//   W1: (ks*8+nt), ks<39, nt<8  = 159744      W2: (ks*4+nt), ks<4, nt<4 = 8192
//   W3: (ks*2+nt), ks<2, nt<2   = 2048
#define E3_U16   20447232u
#define NSWZ     182272

__device__ __forceinline__ u32 bfadj(float x){
    u32 u = __float_as_uint(x);
    return u + 0x7fffu + ((u >> 16) & 1u);
}
__device__ __forceinline__ u32 pk2(float a, float b){
#if __has_builtin(__builtin_amdgcn_cvt_pk_bf16_f32)
    auto t = __builtin_amdgcn_cvt_pk_bf16_f32(a, b);
    u32 r; __builtin_memcpy(&r, &t, 4); return r;
#else
    return __builtin_amdgcn_perm(bfadj(a), bfadj(b), 0x03020706u);
#endif
}
__device__ __forceinline__ u16 f2bf(float f){ return (u16)(bfadj(f) >> 16); }

__device__ __forceinline__ float fexp2(float x){
#if __has_builtin(__builtin_amdgcn_exp2f)
    return __builtin_amdgcn_exp2f(x);
#else
    return exp2f(x);
#endif
}
__device__ __forceinline__ float frcp(float x){
#if __has_builtin(__builtin_amdgcn_rcpf)
    return __builtin_amdgcn_rcpf(x);
#else
    return 1.f / x;
#endif
}

__device__ __forceinline__ void wave_sync(){
    asm volatile("s_waitcnt lgkmcnt(0)" ::: "memory");
}
__device__ __forceinline__ f32x4 mfma16(s16x8 a, s16x8 b, f32x4 c){
    return __builtin_amdgcn_mfma_f32_16x16x32_bf16(a, b, c, 0, 0, 0);
}
__device__ __forceinline__ void store4(u16* p, f32x4 v){
    *(uint2*)p = make_uint2(pk2(v[0], v[1]), pk2(v[2], v[3]));
}

// ================= K0: weight pre-swizzle =================
__global__ void __launch_bounds__(256) swz_kernel(
    const float* __restrict__ wq0, const float* __restrict__ wk0,
    const float* __restrict__ wv0, const float* __restrict__ wr0,
    const float* __restrict__ wq1, const float* __restrict__ wk1,
    const float* __restrict__ wv1, const float* __restrict__ wr1,
    const float* __restrict__ wq2, const float* __restrict__ wk2,
    const float* __restrict__ wv2, const float* __restrict__ wr2,
    const float* __restrict__ w1, const float* __restrict__ w2,
    const float* __restrict__ w3, u16* __restrict__ ws)
{
    int gid = (int)blockIdx.x*256 + (int)threadIdx.x;
    if (gid >= NSWZ) return;
    int w    = gid & 511;
    int lane = w >> 3, j = w & 7;
    int n    = lane & 15, quad = lane >> 4;
    int kin  = quad*8 + j;
    float val;
    if (gid < 12288){
        int mat = gid >> 10;
        int nt  = (gid >> 9) & 1;
        const float* W;
        switch (mat){
            case 0: W = wq0; break; case 1: W = wk0; break;
            case 2: W = wv0; break; case 3: W = wr0; break;
            case 4: W = wq1; break; case 5: W = wk1; break;
            case 6: W = wv1; break; case 7: W = wr1; break;
            case 8: W = wq2; break; case 9: W = wk2; break;
            case 10: W = wv2; break; default: W = wr2; break;
        }
        int din = (mat < 4) ? 16 : 32;
        val = (kin < din) ? W[kin*32 + nt*16 + n] : 0.f;
        if ((mat & 3) == 0) val *= 1.44269504f;   // wq: fold log2e -> exp2 softmax
    } else if (gid < 12288 + 159744){
        int tt = (gid - 12288) >> 9;
        int ks = tt >> 3, nt = tt & 7;
        val = w1[(ks*32 + kin)*128 + nt*16 + n];
    } else if (gid < 12288 + 159744 + 8192){
        int tt = (gid - (12288+159744)) >> 9;
        int ks = tt >> 2, nt = tt & 3;
        val = w2[(ks*32 + kin)*64 + nt*16 + n];
    } else {
        int tt = (gid - (12288+159744+8192)) >> 9;
        int ks = tt >> 1, nt = tt & 1;
        val = w3[(ks*32 + kin)*32 + nt*16 + n];
    }
    ws[E3_U16 + gid] = f2bf(val);
}

// ================= K1: fused attention, 2 samples per wave =================
// Per sample LDS 5120 u16: vBuf(2048, E aliases tiles 0-2) | kBuf(1536) |
// qBuf(1536); pBuf(3072) overlays kBuf+qBuf. Two independent sample streams
// per wave interleave their dependent chains; weight fragments loaded once.
// Block = 2 waves x 2 samples = 4 consecutive samples (full-line E3 writes).
__global__ void __launch_bounds__(128, 2) attn_kernel(
    const int* __restrict__ x, const float* __restrict__ emb,
    u16* __restrict__ ws)
{
    __shared__ __align__(16) u16 lds[2*2*5120];
    const int tid  = (int)threadIdx.x;
    const int wid  = tid >> 6, lane = tid & 63;
    const int h    = lane >> 4, nl = lane & 15;
    const int r0   = (int)blockIdx.x*4 + wid*2;    // wave handles r0, r0+1

    u16* base[2];
    base[0] = lds + wid*10240;
    base[1] = base[0] + 5120;
    const u16* wmat = ws + E3_U16;
    const f32x4 z = {0.f, 0.f, 0.f, 0.f};
    const int A_off = nl*8 + (h>>1)*128 + (h&1)*4;

    // S^T C-init: pad rows g>=39 (mtg=2 tile: g = 32+h*4+reg)
    f32x4 ci;
#pragma unroll
    for (int reg = 0; reg < 4; ++reg)
        ci[reg] = (h*4 + reg >= 7) ? -1e30f : 0.f;

    // ---- embedding gather -> E A-frag (both samples) ----
#pragma unroll
    for (int s = 0; s < 2; ++s){
        u16* eBuf = base[s];
        if (lane < 48){
            int f = lane, mt = f >> 4, fl = f & 15;
            u16* row = eBuf + mt*512 + fl*8;
            if (f < NF){
                const float4* ep = (const float4*)(emb + ((size_t)(x[(r0+s)*NF + f] + f*NVOC))*16);
                float4 e0 = ep[0], e1 = ep[1], e2 = ep[2], e3 = ep[3];
                *(uint4*)(row)       = make_uint4(pk2(e0.x,e0.y), pk2(e0.z,e0.w),
                                                  pk2(e1.x,e1.y), pk2(e1.z,e1.w));
                *(uint4*)(row + 128) = make_uint4(pk2(e2.x,e2.y), pk2(e2.z,e2.w),
                                                  pk2(e3.x,e3.y), pk2(e3.z,e3.w));
            } else {
                *(uint4*)(row)       = make_uint4(0,0,0,0);
                *(uint4*)(row + 128) = make_uint4(0,0,0,0);
            }
            *(uint4*)(row + 256) = make_uint4(0,0,0,0);
            *(uint4*)(row + 384) = make_uint4(0,0,0,0);
        }
        // V pad rows g=48..63 of tile 3 (never clobbered) — zero once
        *(uint2*)(base[s] + 3*512 + 256 + lane*4) = make_uint2(0,0);
    }
    wave_sync();

#pragma unroll 1
    for (int L = 0; L < 3; ++L){
        const u16* wB = wmat + L*4096;
        s16x8 bE[2][3];
#pragma unroll
        for (int s = 0; s < 2; ++s)
#pragma unroll
        for (int nt = 0; nt < 3; ++nt)
            bE[s][nt] = *(const s16x8*)(base[s] + nt*512 + lane*8);
        wave_sync();   // E fully in regs before V writes clobber the region

        // ---- Q^T -> qBuf (weight frags loaded once, used for both samples) ----
        {
            s16x8 a0 = *(const s16x8*)(wB + lane*8);
            s16x8 a1 = *(const s16x8*)(wB + 512 + lane*8);
#pragma unroll
            for (int s = 0; s < 2; ++s){
                u16* qBuf = base[s] + 2048 + 1536;
#pragma unroll
                for (int nt = 0; nt < 3; ++nt){
                    store4(qBuf + nt*512       + A_off, mfma16(a0, bE[s][nt], z));
                    store4(qBuf + nt*512 + 256 + A_off, mfma16(a1, bE[s][nt], z));
                }
            }
        }
        // ---- K^T -> kBuf ----
        {
            s16x8 a0 = *(const s16x8*)(wB + 1024 + lane*8);
            s16x8 a1 = *(const s16x8*)(wB + 1536 + lane*8);
#pragma unroll
            for (int s = 0; s < 2; ++s){
                u16* kBuf = base[s] + 2048;
#pragma unroll
                for (int nt = 0; nt < 3; ++nt){
                    store4(kBuf + nt*512       + A_off, mfma16(a0, bE[s][nt], z));
                    store4(kBuf + nt*512 + 256 + A_off, mfma16(a1, bE[s][nt], z));
                }
            }
        }
        // ---- V -> vBuf (clobbers E region; E already in regs) ----
        {
            s16x8 b0 = *(const s16x8*)(wB + 2048 + lane*8);
            s16x8 b1 = *(const s16x8*)(wB + 2560 + lane*8);
#pragma unroll
            for (int s = 0; s < 2; ++s){
                u16* vBuf = base[s];
#pragma unroll
                for (int mtg = 0; mtg < 3; ++mtg){
                    int toff = (mtg>>1)*1024 + (mtg&1)*256;
                    store4(vBuf + toff       + A_off, mfma16(bE[s][mtg], b0, z));
                    store4(vBuf + toff + 512 + A_off, mfma16(bE[s][mtg], b1, z));
                }
                // zero V pad rows in tile 2 (aliased by E each layer)
                *(uint2*)(vBuf + 2*512 + 256 + lane*4) = make_uint2(0,0);
            }
        }
        // ---- R^T in regs (C layout of O^T) ----
        f32x4 R[2][2][3];
        {
            s16x8 a0 = *(const s16x8*)(wB + 3072 + lane*8);
            s16x8 a1 = *(const s16x8*)(wB + 3584 + lane*8);
#pragma unroll
            for (int s = 0; s < 2; ++s)
#pragma unroll
            for (int nt = 0; nt < 3; ++nt){
                R[s][0][nt] = mfma16(a0, bE[s][nt], z);
                R[s][1][nt] = mfma16(a1, bE[s][nt], z);
            }
        }
        wave_sync();

        // ---- S^T = K x Q^T (9 MFMAs per sample) ----
        f32x4 S[2][3][3];
#pragma unroll
        for (int s = 0; s < 2; ++s){
            u16* kBuf = base[s] + 2048;
            u16* qBuf = kBuf + 1536;
            s16x8 aK[3], bQ[3];
#pragma unroll
            for (int i = 0; i < 3; ++i){
                aK[i] = *(const s16x8*)(kBuf + i*512 + lane*8);
                bQ[i] = *(const s16x8*)(qBuf + i*512 + lane*8);
            }
#pragma unroll
            for (int mtg = 0; mtg < 3; ++mtg)
#pragma unroll
            for (int nt = 0; nt < 3; ++nt)
                S[s][mtg][nt] = mfma16(aK[mtg], bQ[nt], (mtg == 2) ? ci : z);
        }
        // ---- exp2 + rowsum; P stored UNNORMALIZED (inv folded into O) ----
        float inv[2][3];
#pragma unroll
        for (int s = 0; s < 2; ++s)
#pragma unroll
        for (int nt = 0; nt < 3; ++nt){
            float t = 0.f;
#pragma unroll
            for (int mtg = 0; mtg < 3; ++mtg)
#pragma unroll
            for (int reg = 0; reg < 4; ++reg){
                S[s][mtg][nt][reg] = fexp2(S[s][mtg][nt][reg]);
                t += S[s][mtg][nt][reg];
            }
            t += __shfl_xor(t, 16, 64);
            t += __shfl_xor(t, 32, 64);
            inv[s][nt] = frcp(t);
        }
#pragma unroll
        for (int s = 0; s < 2; ++s){
            u16* pBuf = base[s] + 2048;
#pragma unroll
            for (int mtg = 0; mtg < 3; ++mtg)
#pragma unroll
            for (int nt = 0; nt < 3; ++nt)
                store4(pBuf + ((mtg>>1)*3 + nt)*512 + (mtg&1)*256 + A_off,
                       S[s][mtg][nt]);
        }
        wave_sync();

        // ---- O^T = V^T x P~^T (12 MFMAs per sample); o*inv + R in epilogue ----
#pragma unroll
        for (int s = 0; s < 2; ++s){
            u16* vBuf = base[s];
            u16* pBuf = base[s] + 2048;
            s16x8 aV[2][2], bP[2][3];
#pragma unroll
            for (int ks = 0; ks < 2; ++ks){
#pragma unroll
                for (int emt = 0; emt < 2; ++emt)
                    aV[ks][emt] = *(const s16x8*)(vBuf + (ks*2+emt)*512 + lane*8);
#pragma unroll
                for (int nt = 0; nt < 3; ++nt)
                    bP[ks][nt] = *(const s16x8*)(pBuf + (ks*3+nt)*512 + lane*8);
            }
            wave_sync();   // V/P in regs before epilogue overwrites E region
            if (L < 2){
#pragma unroll
                for (int emt = 0; emt < 2; ++emt)
#pragma unroll
                for (int nt = 0; nt < 3; ++nt){
                    f32x4 o = mfma16(aV[1][emt], bP[1][nt],
                             mfma16(aV[0][emt], bP[0][nt], z));
                    float m = (nt < 2 || nl < 7) ? 1.f : 0.f;   // zero cols f>=39
#pragma unroll
                    for (int reg = 0; reg < 4; ++reg)
                        o[reg] = fmaxf(fmaf(o[reg], inv[s][nt], R[s][emt][nt][reg]), 0.f) * m;
                    store4(base[s] + nt*512 + emt*256 + A_off, o);
                }
            } else {
                int rr = r0 + s;
                int st = rr >> 4, sm = rr & 15;
                u32 gbase = (u32)(st*39)*512u + (u32)(sm*8 + (h>>1)*128 + (h&1)*4);
#pragma unroll
                for (int emt = 0; emt < 2; ++emt)
#pragma unroll
                for (int nt = 0; nt < 3; ++nt){
                    f32x4 o = mfma16(aV[1][emt], bP[1][nt],
                             mfma16(aV[0][emt], bP[0][nt], z));
#pragma unroll
                    for (int reg = 0; reg < 4; ++reg)
                        o[reg] = fmaxf(fmaf(o[reg], inv[s][nt], R[s][emt][nt][reg]), 0.f);
                    int f = nt*16 + nl;
                    if (f < NF)
                        *(uint2*)(ws + gbase + (u32)f*512u + emt*256) =
                            make_uint2(pk2(o[0], o[1]), pk2(o[2], o[3]));
                }
            }
        }
        wave_sync();
    }
}

// ================= K2: MLP, 16 samples/block, K-split GEMM1 =================
__global__ void __launch_bounds__(256, 4) mlp_kernel(
    const float* __restrict__ b1, const float* __restrict__ b2,
    const float* __restrict__ b3, const float* __restrict__ w4,
    const float* __restrict__ b4, const u16* __restrict__ ws,
    float* __restrict__ out)
{
    __shared__ __align__(16) float red[8192];
    __shared__ __align__(16) u16 h1t[2048];
    __shared__ __align__(16) u16 h2t[1024];
    __shared__ float part[32];
    const int tid = (int)threadIdx.x;
    const int w   = tid >> 6, lane = tid & 63;
    const int h   = lane >> 4, nl = lane & 15;
    const int st  = (int)blockIdx.x;
    const int A_off = nl*8 + (h>>1)*128 + (h&1)*4;

    const u16* w1b = ws + E3_U16 + 12288u;
    const u16* w2b = w1b + 159744u;
    const u16* w3b = w2b + 8192u;
    const f32x4 z = {0.f,0.f,0.f,0.f};

    // ---- GEMM1: h1^T = w1^T x e3^T, K split across 4 waves ----
    f32x4 acc[8];
#pragma unroll
    for (int nt = 0; nt < 8; ++nt) acc[nt] = z;
#pragma unroll 2
    for (int ks = w; ks < 39; ks += 4){
        s16x8 aE = *(const s16x8*)(ws + (u32)(st*39 + ks)*512u + lane*8);
#pragma unroll
        for (int nt = 0; nt < 8; ++nt){
            s16x8 aW = *(const s16x8*)(w1b + (ks*8 + nt)*512 + lane*8);
            acc[nt] = mfma16(aW, aE, acc[nt]);
        }
    }
#pragma unroll
    for (int nt = 0; nt < 8; ++nt)
        *(f32x4*)(red + (w*8 + nt)*256 + lane*4) = acc[nt];
    __syncthreads();

#pragma unroll
    for (int t = 0; t < 2; ++t){
        int ft = 2*w + t;
        f32x4 s = *(const f32x4*)(red + (0*8 + ft)*256 + lane*4);
#pragma unroll
        for (int p = 1; p < 4; ++p){
            f32x4 q = *(const f32x4*)(red + (p*8 + ft)*256 + lane*4);
#pragma unroll
            for (int reg = 0; reg < 4; ++reg) s[reg] += q[reg];
        }
        float4 bv = *(const float4*)(b1 + ft*16 + h*4);
        f32x4 v;
        v[0] = fmaxf(s[0] + bv.x, 0.f);
        v[1] = fmaxf(s[1] + bv.y, 0.f);
        v[2] = fmaxf(s[2] + bv.z, 0.f);
        v[3] = fmaxf(s[3] + bv.w, 0.f);
        store4(h1t + ft*256 + A_off, v);
    }
    __syncthreads();

    // ---- GEMM2: h2^T = w2^T x h1^T ----
    {
        f32x4 a2 = z;
#pragma unroll
        for (int ks = 0; ks < 4; ++ks){
            s16x8 aW = *(const s16x8*)(w2b + (ks*4 + w)*512 + lane*8);
            s16x8 bH = *(const s16x8*)(h1t + ks*512 + lane*8);
            a2 = mfma16(aW, bH, a2);
        }
        float4 bv = *(const float4*)(b2 + w*16 + h*4);
        f32x4 v;
        v[0] = fmaxf(a2[0] + bv.x, 0.f);
        v[1] = fmaxf(a2[1] + bv.y, 0.f);
        v[2] = fmaxf(a2[2] + bv.z, 0.f);
        v[3] = fmaxf(a2[3] + bv.w, 0.f);
        store4(h2t + (w>>1)*512 + (w&1)*256 + A_off, v);
    }
    __syncthreads();

    // ---- GEMM3 (waves 0,1) + w4 dot ----
    if (w < 2){
        f32x4 a3 = z;
#pragma unroll
        for (int ks = 0; ks < 2; ++ks){
            s16x8 aW = *(const s16x8*)(w3b + (ks*2 + w)*512 + lane*8);
            s16x8 bH = *(const s16x8*)(h2t + ks*512 + lane*8);
            a3 = mfma16(aW, bH, a3);
        }
        float4 b3v = *(const float4*)(b3 + w*16 + h*4);
        float4 w4v = *(const float4*)(w4 + w*16 + h*4);
        float t = fmaxf(a3[0] + b3v.x, 0.f)*w4v.x
                + fmaxf(a3[1] + b3v.y, 0.f)*w4v.y
                + fmaxf(a3[2] + b3v.z, 0.f)*w4v.z
                + fmaxf(a3[3] + b3v.w, 0.f)*w4v.w;
        t += __shfl_xor(t, 16, 64);
        t += __shfl_xor(t, 32, 64);
        if (h == 0) part[w*16 + nl] = t;
    }
    __syncthreads();
    if (tid < 16){
        float zz = part[tid] + part[16 + tid] + b4[0];
        out[st*16 + tid] = 1.f/(1.f + __expf(-zz));
    }
}

extern "C" void kernel_launch(void* const* d_in, const int* in_sizes, int n_in,
                              void* d_out, int out_size, void* d_ws, size_t ws_size,
                              hipStream_t stream)
{
    (void)in_sizes; (void)n_in; (void)ws_size; (void)out_size;
    const int*   x   = (const int*)d_in[0];
    const float* emb = (const float*)d_in[1];
    u16* ws = (u16*)d_ws;

    swz_kernel<<<(NSWZ+255)/256, 256, 0, stream>>>(
        (const float*)d_in[2],  (const float*)d_in[3],  (const float*)d_in[4],  (const float*)d_in[5],
        (const float*)d_in[6],  (const float*)d_in[7],  (const float*)d_in[8],  (const float*)d_in[9],
        (const float*)d_in[10], (const float*)d_in[11], (const float*)d_in[12], (const float*)d_in[13],
        (const float*)d_in[14], (const float*)d_in[16], (const float*)d_in[18], ws);

    attn_kernel<<<NB/4, 128, 0, stream>>>(x, emb, ws);

    mlp_kernel<<<NB/16, 256, 0, stream>>>(
        (const float*)d_in[15], (const float*)d_in[17], (const float*)d_in[19],
        (const float*)d_in[20], (const float*)d_in[21], ws, (float*)d_out);
}

// Round 10
// 184.774 us; speedup vs baseline: 1.1050x; 1.1050x over previous
//
#include <hip/hip_runtime.h>
#include <math.h>

#define NF   39
#define NB   16384
#define NVOC 10000

typedef unsigned short u16;
typedef unsigned int   u32;
typedef float f32x4 __attribute__((ext_vector_type(4)));
typedef short s16x8 __attribute__((ext_vector_type(8)));

// ---- d_ws layout (u16 units) ----
// [0, E3_U16): E3 activations, A-fragment tiles: (st, ks=f) -> 512 u16
// [E3_U16 ...): weights as 512-u16 fragment tiles:
//   12 attn mats (q,k,v,r × 3 layers) × 2 tiles = 12288   (wq pre-scaled by log2e)
//   W1: (ks*8+nt), ks<39, nt<8  = 159744      W2: (ks*4+nt), ks<4, nt<4 = 8192
//   W3: (ks*2+nt), ks<2, nt<2   = 2048
#define E3_U16   20447232u
#define NSWZ     182272

__device__ __forceinline__ u32 bfadj(float x){
    u32 u = __float_as_uint(x);
    return u + 0x7fffu + ((u >> 16) & 1u);
}
__device__ __forceinline__ u32 pk2(float a, float b){
#if __has_builtin(__builtin_amdgcn_cvt_pk_bf16_f32)
    auto t = __builtin_amdgcn_cvt_pk_bf16_f32(a, b);
    u32 r; __builtin_memcpy(&r, &t, 4); return r;
#else
    return __builtin_amdgcn_perm(bfadj(a), bfadj(b), 0x03020706u);
#endif
}
__device__ __forceinline__ u16 f2bf(float f){ return (u16)(bfadj(f) >> 16); }

__device__ __forceinline__ float fexp2(float x){
#if __has_builtin(__builtin_amdgcn_exp2f)
    return __builtin_amdgcn_exp2f(x);
#else
    return exp2f(x);
#endif
}
__device__ __forceinline__ float frcp(float x){
#if __has_builtin(__builtin_amdgcn_rcpf)
    return __builtin_amdgcn_rcpf(x);
#else
    return 1.f / x;
#endif
}

__device__ __forceinline__ void wave_sync(){
    asm volatile("s_waitcnt lgkmcnt(0)" ::: "memory");
}
__device__ __forceinline__ f32x4 mfma16(s16x8 a, s16x8 b, f32x4 c){
    return __builtin_amdgcn_mfma_f32_16x16x32_bf16(a, b, c, 0, 0, 0);
}
__device__ __forceinline__ void store4(u16* p, f32x4 v){
    *(uint2*)p = make_uint2(pk2(v[0], v[1]), pk2(v[2], v[3]));
}

// ================= K0: weight pre-swizzle =================
__global__ void __launch_bounds__(256) swz_kernel(
    const float* __restrict__ wq0, const float* __restrict__ wk0,
    const float* __restrict__ wv0, const float* __restrict__ wr0,
    const float* __restrict__ wq1, const float* __restrict__ wk1,
    const float* __restrict__ wv1, const float* __restrict__ wr1,
    const float* __restrict__ wq2, const float* __restrict__ wk2,
    const float* __restrict__ wv2, const float* __restrict__ wr2,
    const float* __restrict__ w1, const float* __restrict__ w2,
    const float* __restrict__ w3, u16* __restrict__ ws)
{
    int gid = (int)blockIdx.x*256 + (int)threadIdx.x;
    if (gid >= NSWZ) return;
    int w    = gid & 511;
    int lane = w >> 3, j = w & 7;
    int n    = lane & 15, quad = lane >> 4;
    int kin  = quad*8 + j;
    float val;
    if (gid < 12288){
        int mat = gid >> 10;
        int nt  = (gid >> 9) & 1;
        const float* W;
        switch (mat){
            case 0: W = wq0; break; case 1: W = wk0; break;
            case 2: W = wv0; break; case 3: W = wr0; break;
            case 4: W = wq1; break; case 5: W = wk1; break;
            case 6: W = wv1; break; case 7: W = wr1; break;
            case 8: W = wq2; break; case 9: W = wk2; break;
            case 10: W = wv2; break; default: W = wr2; break;
        }
        int din = (mat < 4) ? 16 : 32;
        val = (kin < din) ? W[kin*32 + nt*16 + n] : 0.f;
        if ((mat & 3) == 0) val *= 1.44269504f;   // wq: fold log2e -> exp2 softmax
    } else if (gid < 12288 + 159744){
        int tt = (gid - 12288) >> 9;
        int ks = tt >> 3, nt = tt & 7;
        val = w1[(ks*32 + kin)*128 + nt*16 + n];
    } else if (gid < 12288 + 159744 + 8192){
        int tt = (gid - (12288+159744)) >> 9;
        int ks = tt >> 2, nt = tt & 3;
        val = w2[(ks*32 + kin)*64 + nt*16 + n];
    } else {
        int tt = (gid - (12288+159744+8192)) >> 9;
        int ks = tt >> 1, nt = tt & 1;
        val = w3[(ks*32 + kin)*32 + nt*16 + n];
    }
    ws[E3_U16 + gid] = f2bf(val);
}

// ================= K1: fused attention (round-7 structure) =================
// Per-wave LDS 5120 u16: vBuf(2048, E aliases tiles 0-2) | kBuf(1536) | qBuf(1536)
// pBuf(3072) overlays kBuf+qBuf. 4 waves/block, 1 sample/wave.
__global__ void __launch_bounds__(256, 4) attn_kernel(
    const int* __restrict__ x, const float* __restrict__ emb,
    u16* __restrict__ ws)
{
    __shared__ __align__(16) u16 lds[4*5120];
    const int tid  = (int)threadIdx.x;
    const int wid  = tid >> 6, lane = tid & 63;
    const int h    = lane >> 4, nl = lane & 15;
    const int r    = (int)blockIdx.x*4 + wid;

    u16* vBuf = lds + wid*5120;   // 2048: V B-frag (ks*2+emt); tiles 0-2 alias E
    u16* eBuf = vBuf;             // 1536: E A-frag (B-frag of E^T)
    u16* kBuf = vBuf + 2048;      // 1536: K (B-frag of K^T)
    u16* qBuf = kBuf + 1536;      // 1536: Q^T B-frag
    u16* pBuf = kBuf;             // 3072: P^T B-frag (ks*3+nt) overlays K+Q
    const u16* wmat = ws + E3_U16;
    const f32x4 z = {0.f, 0.f, 0.f, 0.f};
    const int A_off = nl*8 + (h>>1)*128 + (h&1)*4;

    // S^T C-init: pad rows g>=39 (mtg=2 tile: g = 32+h*4+reg)
    f32x4 ci;
#pragma unroll
    for (int reg = 0; reg < 4; ++reg)
        ci[reg] = (h*4 + reg >= 7) ? -1e30f : 0.f;

    // ---- embedding gather -> E A-frag ----
    if (lane < 48){
        int f = lane, mt = f >> 4, fl = f & 15;
        u16* row = eBuf + mt*512 + fl*8;
        if (f < NF){
            const float4* ep = (const float4*)(emb + ((size_t)(x[r*NF + f] + f*NVOC))*16);
            float4 e0 = ep[0], e1 = ep[1], e2 = ep[2], e3 = ep[3];
            *(uint4*)(row)       = make_uint4(pk2(e0.x,e0.y), pk2(e0.z,e0.w),
                                              pk2(e1.x,e1.y), pk2(e1.z,e1.w));
            *(uint4*)(row + 128) = make_uint4(pk2(e2.x,e2.y), pk2(e2.z,e2.w),
                                              pk2(e3.x,e3.y), pk2(e3.z,e3.w));
        } else {
            *(uint4*)(row)       = make_uint4(0,0,0,0);
            *(uint4*)(row + 128) = make_uint4(0,0,0,0);
        }
        *(uint4*)(row + 256) = make_uint4(0,0,0,0);
        *(uint4*)(row + 384) = make_uint4(0,0,0,0);
    }
    // V pad rows g=48..63 of tile 3 (never clobbered by E) — zero once
    *(uint2*)(vBuf + 3*512 + 256 + lane*4) = make_uint2(0,0);
    wave_sync();

#pragma unroll 1
    for (int L = 0; L < 3; ++L){
        const u16* wB = wmat + L*4096;
        s16x8 bE[3];
#pragma unroll
        for (int nt = 0; nt < 3; ++nt)
            bE[nt] = *(const s16x8*)(eBuf + nt*512 + lane*8);
        wave_sync();   // E fully in regs before V writes clobber the region

        // ---- Q^T -> qBuf ----
        {
            s16x8 a0 = *(const s16x8*)(wB + lane*8);
            s16x8 a1 = *(const s16x8*)(wB + 512 + lane*8);
#pragma unroll
            for (int nt = 0; nt < 3; ++nt){
                store4(qBuf + nt*512       + A_off, mfma16(a0, bE[nt], z));
                store4(qBuf + nt*512 + 256 + A_off, mfma16(a1, bE[nt], z));
            }
        }
        // ---- K^T -> kBuf ----
        {
            s16x8 a0 = *(const s16x8*)(wB + 1024 + lane*8);
            s16x8 a1 = *(const s16x8*)(wB + 1536 + lane*8);
#pragma unroll
            for (int nt = 0; nt < 3; ++nt){
                store4(kBuf + nt*512       + A_off, mfma16(a0, bE[nt], z));
                store4(kBuf + nt*512 + 256 + A_off, mfma16(a1, bE[nt], z));
            }
        }
        // ---- V -> vBuf (clobbers E region; E already in bE regs) ----
        {
            s16x8 b0 = *(const s16x8*)(wB + 2048 + lane*8);
            s16x8 b1 = *(const s16x8*)(wB + 2560 + lane*8);
#pragma unroll
            for (int mtg = 0; mtg < 3; ++mtg){
                int toff = (mtg>>1)*1024 + (mtg&1)*256;
                store4(vBuf + toff       + A_off, mfma16(bE[mtg], b0, z));
                store4(vBuf + toff + 512 + A_off, mfma16(bE[mtg], b1, z));
            }
            // zero V pad rows in tile 2 (aliased by E each layer)
            *(uint2*)(vBuf + 2*512 + 256 + lane*4) = make_uint2(0,0);
        }
        // ---- R^T in regs (C layout of O^T) ----
        f32x4 R[2][3];
        {
            s16x8 a0 = *(const s16x8*)(wB + 3072 + lane*8);
            s16x8 a1 = *(const s16x8*)(wB + 3584 + lane*8);
#pragma unroll
            for (int nt = 0; nt < 3; ++nt){
                R[0][nt] = mfma16(a0, bE[nt], z);
                R[1][nt] = mfma16(a1, bE[nt], z);
            }
        }
        wave_sync();

        // ---- S^T = K x Q^T (9 MFMAs); logits already in log2 domain ----
        f32x4 S[3][3];
        {
            s16x8 aK[3], bQ[3];
#pragma unroll
            for (int i = 0; i < 3; ++i){
                aK[i] = *(const s16x8*)(kBuf + i*512 + lane*8);
                bQ[i] = *(const s16x8*)(qBuf + i*512 + lane*8);
            }
#pragma unroll
            for (int mtg = 0; mtg < 3; ++mtg)
#pragma unroll
            for (int nt = 0; nt < 3; ++nt)
                S[mtg][nt] = mfma16(aK[mtg], bQ[nt], (mtg == 2) ? ci : z);
        }
        // ---- exp2 + rowsum; P stored UNNORMALIZED (inv folded into O) ----
        float inv[3];
#pragma unroll
        for (int nt = 0; nt < 3; ++nt){
            float t = 0.f;
#pragma unroll
            for (int mtg = 0; mtg < 3; ++mtg)
#pragma unroll
            for (int reg = 0; reg < 4; ++reg){
                S[mtg][nt][reg] = fexp2(S[mtg][nt][reg]);
                t += S[mtg][nt][reg];
            }
            t += __shfl_xor(t, 16, 64);
            t += __shfl_xor(t, 32, 64);
            inv[nt] = frcp(t);
        }
#pragma unroll
        for (int mtg = 0; mtg < 3; ++mtg)
#pragma unroll
        for (int nt = 0; nt < 3; ++nt)
            store4(pBuf + ((mtg>>1)*3 + nt)*512 + (mtg&1)*256 + A_off, S[mtg][nt]);
        wave_sync();

        // ---- O^T = V^T x P~^T (12 MFMAs); o*inv + R in epilogue ----
        s16x8 aV[2][2], bP[2][3];
#pragma unroll
        for (int ks = 0; ks < 2; ++ks){
#pragma unroll
            for (int emt = 0; emt < 2; ++emt)
                aV[ks][emt] = *(const s16x8*)(vBuf + (ks*2+emt)*512 + lane*8);
#pragma unroll
            for (int nt = 0; nt < 3; ++nt)
                bP[ks][nt] = *(const s16x8*)(pBuf + (ks*3+nt)*512 + lane*8);
        }
        wave_sync();   // all V/P reads in regs before epilogue overwrites E region
        if (L < 2){
#pragma unroll
            for (int emt = 0; emt < 2; ++emt)
#pragma unroll
            for (int nt = 0; nt < 3; ++nt){
                f32x4 o = mfma16(aV[1][emt], bP[1][nt],
                         mfma16(aV[0][emt], bP[0][nt], z));
                float m = (nt < 2 || nl < 7) ? 1.f : 0.f;   // zero cols f>=39
#pragma unroll
                for (int reg = 0; reg < 4; ++reg)
                    o[reg] = fmaxf(fmaf(o[reg], inv[nt], R[emt][nt][reg]), 0.f) * m;
                store4(eBuf + nt*512 + emt*256 + A_off, o);
            }
        } else {
            int st = r >> 4, sm = r & 15;
            u32 base = (u32)(st*39)*512u + (u32)(sm*8 + (h>>1)*128 + (h&1)*4);
#pragma unroll
            for (int emt = 0; emt < 2; ++emt)
#pragma unroll
            for (int nt = 0; nt < 3; ++nt){
                f32x4 o = mfma16(aV[1][emt], bP[1][nt],
                         mfma16(aV[0][emt], bP[0][nt], z));
#pragma unroll
                for (int reg = 0; reg < 4; ++reg)
                    o[reg] = fmaxf(fmaf(o[reg], inv[nt], R[emt][nt][reg]), 0.f);
                int f = nt*16 + nl;
                if (f < NF)
                    *(uint2*)(ws + base + (u32)f*512u + emt*256) =
                        make_uint2(pk2(o[0], o[1]), pk2(o[2], o[3]));
            }
        }
        wave_sync();
    }
}

// ================= K2: MLP, 16 samples/block, K-split GEMM1 =================
__global__ void __launch_bounds__(256, 4) mlp_kernel(
    const float* __restrict__ b1, const float* __restrict__ b2,
    const float* __restrict__ b3, const float* __restrict__ w4,
    const float* __restrict__ b4, const u16* __restrict__ ws,
    float* __restrict__ out)
{
    __shared__ __align__(16) float red[8192];
    __shared__ __align__(16) u16 h1t[2048];
    __shared__ __align__(16) u16 h2t[1024];
    __shared__ float part[32];
    const int tid = (int)threadIdx.x;
    const int w   = tid >> 6, lane = tid & 63;
    const int h   = lane >> 4, nl = lane & 15;
    const int st  = (int)blockIdx.x;
    const int A_off = nl*8 + (h>>1)*128 + (h&1)*4;

    const u16* w1b = ws + E3_U16 + 12288u;
    const u16* w2b = w1b + 159744u;
    const u16* w3b = w2b + 8192u;
    const f32x4 z = {0.f,0.f,0.f,0.f};

    // ---- GEMM1: h1^T = w1^T x e3^T, K split across 4 waves ----
    f32x4 acc[8];
#pragma unroll
    for (int nt = 0; nt < 8; ++nt) acc[nt] = z;
#pragma unroll 2
    for (int ks = w; ks < 39; ks += 4){
        s16x8 aE = *(const s16x8*)(ws + (u32)(st*39 + ks)*512u + lane*8);
#pragma unroll
        for (int nt = 0; nt < 8; ++nt){
            s16x8 aW = *(const s16x8*)(w1b + (ks*8 + nt)*512 + lane*8);
            acc[nt] = mfma16(aW, aE, acc[nt]);
        }
    }
#pragma unroll
    for (int nt = 0; nt < 8; ++nt)
        *(f32x4*)(red + (w*8 + nt)*256 + lane*4) = acc[nt];
    __syncthreads();

#pragma unroll
    for (int t = 0; t < 2; ++t){
        int ft = 2*w + t;
        f32x4 s = *(const f32x4*)(red + (0*8 + ft)*256 + lane*4);
#pragma unroll
        for (int p = 1; p < 4; ++p){
            f32x4 q = *(const f32x4*)(red + (p*8 + ft)*256 + lane*4);
#pragma unroll
            for (int reg = 0; reg < 4; ++reg) s[reg] += q[reg];
        }
        float4 bv = *(const float4*)(b1 + ft*16 + h*4);
        f32x4 v;
        v[0] = fmaxf(s[0] + bv.x, 0.f);
        v[1] = fmaxf(s[1] + bv.y, 0.f);
        v[2] = fmaxf(s[2] + bv.z, 0.f);
        v[3] = fmaxf(s[3] + bv.w, 0.f);
        store4(h1t + ft*256 + A_off, v);
    }
    __syncthreads();

    // ---- GEMM2: h2^T = w2^T x h1^T ----
    {
        f32x4 a2 = z;
#pragma unroll
        for (int ks = 0; ks < 4; ++ks){
            s16x8 aW = *(const s16x8*)(w2b + (ks*4 + w)*512 + lane*8);
            s16x8 bH = *(const s16x8*)(h1t + ks*512 + lane*8);
            a2 = mfma16(aW, bH, a2);
        }
        float4 bv = *(const float4*)(b2 + w*16 + h*4);
        f32x4 v;
        v[0] = fmaxf(a2[0] + bv.x, 0.f);
        v[1] = fmaxf(a2[1] + bv.y, 0.f);
        v[2] = fmaxf(a2[2] + bv.z, 0.f);
        v[3] = fmaxf(a2[3] + bv.w, 0.f);
        store4(h2t + (w>>1)*512 + (w&1)*256 + A_off, v);
    }
    __syncthreads();

    // ---- GEMM3 (waves 0,1) + w4 dot ----
    if (w < 2){
        f32x4 a3 = z;
#pragma unroll
        for (int ks = 0; ks < 2; ++ks){
            s16x8 aW = *(const s16x8*)(w3b + (ks*2 + w)*512 + lane*8);
            s16x8 bH = *(const s16x8*)(h2t + ks*512 + lane*8);
            a3 = mfma16(aW, bH, a3);
        }
        float4 b3v = *(const float4*)(b3 + w*16 + h*4);
        float4 w4v = *(const float4*)(w4 + w*16 + h*4);
        float t = fmaxf(a3[0] + b3v.x, 0.f)*w4v.x
                + fmaxf(a3[1] + b3v.y, 0.f)*w4v.y
                + fmaxf(a3[2] + b3v.z, 0.f)*w4v.z
                + fmaxf(a3[3] + b3v.w, 0.f)*w4v.w;
        t += __shfl_xor(t, 16, 64);
        t += __shfl_xor(t, 32, 64);
        if (h == 0) part[w*16 + nl] = t;
    }
    __syncthreads();
    if (tid < 16){
        float zz = part[tid] + part[16 + tid] + b4[0];
        out[st*16 + tid] = 1.f/(1.f + __expf(-zz));
    }
}

extern "C" void kernel_launch(void* const* d_in, const int* in_sizes, int n_in,
                              void* d_out, int out_size, void* d_ws, size_t ws_size,
                              hipStream_t stream)
{
    (void)in_sizes; (void)n_in; (void)ws_size; (void)out_size;
    const int*   x   = (const int*)d_in[0];
    const float* emb = (const float*)d_in[1];
    u16* ws = (u16*)d_ws;

    swz_kernel<<<(NSWZ+255)/256, 256, 0, stream>>>(
        (const float*)d_in[2],  (const float*)d_in[3],  (const float*)d_in[4],  (const float*)d_in[5],
        (const float*)d_in[6],  (const float*)d_in[7],  (const float*)d_in[8],  (const float*)d_in[9],
        (const float*)d_in[10], (const float*)d_in[11], (const float*)d_in[12], (const float*)d_in[13],
        (const float*)d_in[14], (const float*)d_in[16], (const float*)d_in[18], ws);

    attn_kernel<<<NB/4, 256, 0, stream>>>(x, emb, ws);

    mlp_kernel<<<NB/16, 256, 0, stream>>>(
        (const float*)d_in[15], (const float*)d_in[17], (const float*)d_in[19],
        (const float*)d_in[20], (const float*)d_in[21], ws, (float*)d_out);
}